// Round 10
// baseline (207.681 us; speedup 1.0000x reference)
//
#include <hip/hip_runtime.h>
#include <hip/hip_bf16.h>
#include <stdint.h>

#define NSK 1000
#define TT  200
#define BB  64
#define NROW (BB * TT)      // 12800
#define NOUT (BB * (TT-1))  // 12736
#define CH  8               // scan pipeline depth (steps)
#define RW  8               // scan Mv rows per wave
#define NW  800             // wea-role blocks (16 rows each)
#define NS  128             // scan-role blocks (2 per batch)
#define NFP 796             // blocks that also run fp (16 outputs each)
#define NBLK (NW + NS)      // 928 <= 4 blocks/CU * 256 CUs -> all co-resident

__device__ __forceinline__ float lane_bcast(float v, int l) {
  return __uint_as_float(__builtin_amdgcn_readlane(__float_as_uint(v), l));
}
__device__ __forceinline__ unsigned ulane_bcast(unsigned v, int l) {
  return __builtin_amdgcn_readlane(v, l);
}
__device__ __forceinline__ float frcp(float x) { return __builtin_amdgcn_rcpf(x); }
__device__ __forceinline__ float sigm(float x) { return frcp(1.f + __expf(-x)); }
__device__ __forceinline__ float tanh_fast(float x) {
  return fmaf(-2.f, frcp(1.f + __expf(2.f * x)), 1.f);   // 1 - 2/(1+e^2x)
}

typedef _Float16 half2v __attribute__((ext_vector_type(2)));
union H2U { unsigned u; half2v h; };
__device__ __forceinline__ unsigned pack2h(float a, float b) {
  H2U x; x.h = (half2v){(_Float16)a, (_Float16)b}; return x.u;
}
__device__ __forceinline__ float dot2h(unsigned sp, unsigned wp, float acc) {
#if __has_builtin(__builtin_amdgcn_fdot2)
  H2U s, w; s.u = sp; w.u = wp;
  return __builtin_amdgcn_fdot2(s.h, w.h, acc, false);
#else
  H2U s, w; s.u = sp; w.u = wp;
  return fmaf((float)s.h.y, (float)w.h.y, fmaf((float)s.h.x, (float)w.h.x, acc));
#endif
}
__device__ __forceinline__ unsigned pack_pairs(float v) {
  const int lane = threadIdx.x & 63;
  float a = __shfl(v, 2 * lane);       // lanes 0..31 cover all 32 pairs
  float b = __shfl(v, 2 * lane + 1);
  return pack2h(a, b);
}

__device__ __forceinline__ void spin_ge(unsigned* p, unsigned tgt) {
  while (__hip_atomic_load(p, __ATOMIC_RELAXED, __HIP_MEMORY_SCOPE_AGENT) < tgt)
    __builtin_amdgcn_s_sleep(8);
}

// ---- scan helpers (R9-proven) ----
__device__ __forceinline__ void load_chunk(
    const float* __restrict__ wr, const float* __restrict__ er,
    const float* __restrict__ ar, int t0, int wl, int lane,
    float* wb, float* ebf, float* abf)
{
  #pragma unroll
  for (int k = 0; k < CH; ++k) {
    wb[k]  = wr[(t0 + k) * 64 + wl];
    ebf[k] = er[(t0 + k) * 64 + lane];
    abf[k] = ar[(t0 + k) * 64 + lane];
  }
}

__device__ __forceinline__ void compute_chunk(
    float* Mv, const float* wb, const float* ebf, const float* abf,
    float* __restrict__ red, int wave, int lane)
{
  #pragma unroll
  for (int k = 0; k < CH; ++k) {
    const float wv = wb[k], ev = ebf[k], av = abf[k];
    float rp = 0.f;
    #pragma unroll
    for (int i = 0; i < RW; ++i) {
      float wm = lane_bcast(wv, i);        // w[m0+i] sits in lane i (0..7)
      rp = fmaf(wm, Mv[i], rp);            // read uses PRE-update Mv
      float tp = fmaf(-ev, Mv[i], av);     // a - e*Mv
      Mv[i] = fmaf(wm, tp, Mv[i]);         // Mv += w*(a - e*Mv)
    }
    red[k * 256 + wave * 64 + lane] = rp;
  }
}

__device__ __forceinline__ void reduce_store(
    const float* __restrict__ red, int ch, int b, int s, int wave, int lane,
    float* __restrict__ part_ws)
{
  #pragma unroll
  for (int u = 0; u < 2; ++u) {
    const float* rr = red + (wave * 2 + u) * 256;
    const float v = (rr[lane] + rr[64 + lane]) + (rr[128 + lane] + rr[192 + lane]);
    const int t = ch * CH + wave * 2 + u;
    part_ws[((size_t)b * TT + t) * 128 + s * 64 + lane] = v;
  }
}

// Single-launch pipeline. Blocks 0..799: wea (16 rows) -> release wcnt -> fp (16 outputs,
// waits on scnt). Blocks 800..927: scan (waits on wcnt) -> release scnt.
// All 928 blocks co-resident (<=128 VGPR, <=30KB LDS, 4 blocks/CU) => spins cannot deadlock.
__global__ __launch_bounds__(256, 4) void dkvmn_pipe(
    const int* __restrict__ skills, const int* __restrict__ responses,
    const float* __restrict__ k_emb, const float* __restrict__ v_emb,
    const float* __restrict__ Mk, const float* __restrict__ Mv0,
    const float* __restrict__ fW, const float* __restrict__ fb,
    const float* __restrict__ eW, const float* __restrict__ eb,
    const float* __restrict__ aW, const float* __restrict__ ab,
    const float* __restrict__ pW, const float* __restrict__ pb,
    unsigned* __restrict__ wcnt, unsigned* __restrict__ scnt,
    float* __restrict__ w_ws, float* __restrict__ e_ws, float* __restrict__ a_ws,
    float* __restrict__ part_ws, float* __restrict__ out)
{
  __shared__ unsigned smem[7680];                    // 30720 B (weights / red / fW)
  const int tid = threadIdx.x;
  const int wave = tid >> 6, lane = tid & 63;

  if (blockIdx.x >= NW) {
    // ================= scan role =================
    const int j = blockIdx.x - NW, b = j >> 1, s = j & 1;
    if (tid == 0) { spin_ge(&wcnt[b], 200u); __threadfence(); }  // acquire batch b
    __syncthreads();

    const int m0 = s * 32 + wave * RW;
    const int wl = m0 + (lane & (RW - 1));
    float Mv[RW];
    #pragma unroll
    for (int i = 0; i < RW; ++i) Mv[i] = Mv0[(size_t)(m0 + i) * 64 + lane];

    const float* wr = w_ws + (size_t)b * TT * 64;
    const float* er = e_ws + (size_t)b * TT * 64;
    const float* ar = a_ws + (size_t)b * TT * 64;
    float* red0 = (float*)smem;                     // CH*256 floats
    float* red1 = red0 + CH * 256;

    float wb0[CH], eb0[CH], ab0[CH];
    float wb1[CH], eb1[CH], ab1[CH];
    load_chunk(wr, er, ar, 0, wl, lane, wb0, eb0, ab0);
    for (int ch = 0; ch < TT / CH; ch += 2) {
      if ((ch + 1) * CH < TT)
        load_chunk(wr, er, ar, (ch + 1) * CH, wl, lane, wb1, eb1, ab1);
      compute_chunk(Mv, wb0, eb0, ab0, red0, wave, lane);
      __syncthreads();
      reduce_store(red0, ch, b, s, wave, lane, part_ws);
      if ((ch + 2) * CH < TT)
        load_chunk(wr, er, ar, (ch + 2) * CH, wl, lane, wb0, eb0, ab0);
      if ((ch + 1) * CH < TT) {
        compute_chunk(Mv, wb1, eb1, ab1, red1, wave, lane);
        __syncthreads();
        reduce_store(red1, ch + 1, b, s, wave, lane, part_ws);
      }
    }
    __syncthreads();
    if (tid == 0) {
      __threadfence();                               // release partials
      __hip_atomic_fetch_add(&scnt[b], 1u, __ATOMIC_RELEASE, __HIP_MEMORY_SCOPE_AGENT);
    }
    return;
  }

  // ================= wea role (16 rows/block, 4/wave) =================
  for (int ch = tid; ch < 1536; ch += 256) {         // f16-pack 3x 64x64, stride 40
    const int mat = ch >> 9, rem = ch & 511;
    const int j = rem >> 3, cc = rem & 7;
    const float4* src = (mat == 0) ? (const float4*)Mk
                      : (mat == 1) ? (const float4*)eW : (const float4*)aW;
    const float4 f0 = src[j * 16 + cc * 2];
    const float4 f1 = src[j * 16 + cc * 2 + 1];
    uint4 pk;
    pk.x = pack2h(f0.x, f0.y); pk.y = pack2h(f0.z, f0.w);
    pk.z = pack2h(f1.x, f1.y); pk.w = pack2h(f1.z, f1.w);
    *(uint4*)&smem[mat * 2560 + j * 40 + ((cc + j) & 7) * 4] = pk;
  }
  __syncthreads();
  {
    const float ebl = eb[lane], abl = ab[lane];
    const int r0 = blockIdx.x * 16 + wave * 4;       // 800*16 = 12800 rows exact

    float kv[4], vv[4];
    #pragma unroll
    for (int i = 0; i < 4; ++i) {
      const int sk = skills[r0 + i];
      int rr = responses[r0 + i]; rr = (rr > -1) ? rr : 0;   // masked_r
      kv[i] = k_emb[(size_t)sk * 64 + lane];
      vv[i] = v_emb[(size_t)(sk + NSK * rr) * 64 + lane];
    }
    unsigned kp[4], vp[4];
    #pragma unroll
    for (int i = 0; i < 4; ++i) { kp[i] = pack_pairs(kv[i]); vp[i] = pack_pairs(vv[i]); }

    float accK[4] = {0,0,0,0}, accE[4] = {0,0,0,0}, accA[4] = {0,0,0,0};
    #pragma unroll 1
    for (int h = 0; h < 2; ++h) {                    // halves: 4 uint4 chunks (32 dims)
      uint4 qm[4], qe[4], qa[4];
      #pragma unroll
      for (int c = 0; c < 4; ++c) {
        const int off = lane * 40 + (((h * 4 + c) + lane) & 7) * 4;
        qm[c] = *(const uint4*)&smem[off];
        qe[c] = *(const uint4*)&smem[2560 + off];
        qa[c] = *(const uint4*)&smem[5120 + off];
      }
      #pragma unroll
      for (int i = 0; i < 4; ++i) {
        #pragma unroll
        for (int c = 0; c < 4; ++c) {
          const unsigned um[4] = {qm[c].x, qm[c].y, qm[c].z, qm[c].w};
          const unsigned ue[4] = {qe[c].x, qe[c].y, qe[c].z, qe[c].w};
          const unsigned ua[4] = {qa[c].x, qa[c].y, qa[c].z, qa[c].w};
          #pragma unroll
          for (int m = 0; m < 4; ++m) {
            const int idx = (h * 4 + c) * 4 + m;     // pair index 0..31
            const unsigned spk = ulane_bcast(kp[i], idx);
            const unsigned spv = ulane_bcast(vp[i], idx);
            accK[i] = dot2h(spk, um[m], accK[i]);
            accE[i] = dot2h(spv, ue[m], accE[i]);
            accA[i] = dot2h(spv, ua[m], accA[i]);
          }
        }
      }
    }
    #pragma unroll
    for (int i = 0; i < 4; ++i) {
      const int row = r0 + i;
      float mx = accK[i];
      #pragma unroll
      for (int off = 32; off; off >>= 1) mx = fmaxf(mx, __shfl_xor(mx, off));
      float ex = __expf(accK[i] - mx);
      float sm = ex;
      #pragma unroll
      for (int off = 32; off; off >>= 1) sm += __shfl_xor(sm, off);
      w_ws[(size_t)row * 64 + lane] = ex * frcp(sm);
      e_ws[(size_t)row * 64 + lane] = sigm(accE[i] + ebl);
      a_ws[(size_t)row * 64 + lane] = tanh_fast(accA[i] + abl);
    }
  }
  __syncthreads();
  if (tid == 0) {
    __threadfence();                                 // release w/e/a
    const int r0 = blockIdx.x * 16;
    const int b0 = r0 / TT, b1 = (r0 + 15) / TT;
    if (b0 == b1) {
      __hip_atomic_fetch_add(&wcnt[b0], 16u, __ATOMIC_RELEASE, __HIP_MEMORY_SCOPE_AGENT);
    } else {
      const unsigned n0 = (unsigned)((b0 + 1) * TT - r0);
      __hip_atomic_fetch_add(&wcnt[b0], n0, __ATOMIC_RELEASE, __HIP_MEMORY_SCOPE_AGENT);
      __hip_atomic_fetch_add(&wcnt[b1], 16u - n0, __ATOMIC_RELEASE, __HIP_MEMORY_SCOPE_AGENT);
    }
  }

  if (blockIdx.x >= NFP) return;

  // ================= fp role (8 pairs/block = 16 outputs) =================
  {
    const int idx0 = blockIdx.x * 16, idx1 = idx0 + 15;
    const int bf = idx0 / 199, bl = idx1 / 199;
    if (tid == 0) {
      spin_ge(&scnt[bf], 2u);
      if (bl != bf) spin_ge(&scnt[bl], 2u);
      __threadfence();                               // acquire partials
    }
    __syncthreads();
    for (int ch = tid; ch < 1024; ch += 256) {       // restage fW f16, stride 72
      const int j = ch >> 4, cc = ch & 15;
      const float4 f0 = ((const float4*)fW)[j * 32 + cc * 2];
      const float4 f1 = ((const float4*)fW)[j * 32 + cc * 2 + 1];
      uint4 pk;
      pk.x = pack2h(f0.x, f0.y); pk.y = pack2h(f0.z, f0.w);
      pk.z = pack2h(f1.x, f1.y); pk.w = pack2h(f1.z, f1.w);
      *(uint4*)&smem[j * 72 + ((cc + j) & 15) * 4] = pk;
    }
    __syncthreads();

    const float fbl = fb[lane], pwl = pW[lane], pb0 = pb[0];
    #pragma unroll 1
    for (int pi = 0; pi < 2; ++pi) {
      const int p = blockIdx.x * 8 + wave * 2 + pi;  // pair id < 6368
      float pc[2][2], kc[2];
      int bsave[2], tsave[2];
      #pragma unroll
      for (int i = 0; i < 2; ++i) {
        const unsigned idx = 2u * p + i;
        const unsigned b = idx / 199u;
        const int row = (int)(idx + b + 1u);
        bsave[i] = (int)b; tsave[i] = (int)(idx - b * 199u);
        const float* pp = part_ws + (size_t)row * 128;
        pc[i][0] = pp[lane]; pc[i][1] = pp[64 + lane];
        kc[i] = k_emb[(size_t)skills[row] * 64 + lane];
      }
      unsigned rvp[2], kvp[2];
      #pragma unroll
      for (int i = 0; i < 2; ++i) {
        rvp[i] = pack_pairs(pc[i][0] + pc[i][1]);
        kvp[i] = pack_pairs(kc[i]);
      }
      float acc[2] = {fbl, fbl};
      #pragma unroll 1
      for (int h = 0; h < 4; ++h) {                  // quarters: 4 uint4 (32 inputs)
        uint4 qf[4];
        #pragma unroll
        for (int c = 0; c < 4; ++c)
          qf[c] = *(const uint4*)&smem[lane * 72 + (((h * 4 + c) + lane) & 15) * 4];
        #pragma unroll
        for (int i = 0; i < 2; ++i) {
          #pragma unroll
          for (int c = 0; c < 4; ++c) {
            const unsigned uu[4] = {qf[c].x, qf[c].y, qf[c].z, qf[c].w};
            #pragma unroll
            for (int m = 0; m < 4; ++m) {
              const int idx = (h * 4 + c) * 4 + m;   // pair index 0..63
              const unsigned sp = (idx < 32) ? ulane_bcast(rvp[i], idx)
                                             : ulane_bcast(kvp[i], idx - 32);
              acc[i] = dot2h(sp, uu[m], acc[i]);
            }
          }
        }
      }
      float f0 = tanh_fast(acc[0]) * pwl;
      float f1 = tanh_fast(acc[1]) * pwl;
      #pragma unroll
      for (int off = 32; off; off >>= 1) {
        f0 += __shfl_xor(f0, off);
        f1 += __shfl_xor(f1, off);
      }
      if (lane == 0) {
        out[(size_t)bsave[0] * (TT - 1) + tsave[0]] = sigm(f0 + pb0);
        out[(size_t)bsave[1] * (TT - 1) + tsave[1]] = sigm(f1 + pb0);
      }
    }
  }
}

extern "C" void kernel_launch(void* const* d_in, const int* in_sizes, int n_in,
                              void* d_out, int out_size, void* d_ws, size_t ws_size,
                              hipStream_t stream) {
  const int* skills    = (const int*)d_in[0];
  const int* responses = (const int*)d_in[1];
  const float* k_emb   = (const float*)d_in[2];
  const float* v_emb   = (const float*)d_in[3];
  const float* Mk      = (const float*)d_in[4];
  const float* Mv0     = (const float*)d_in[5];
  const float* fW      = (const float*)d_in[6];
  const float* fb      = (const float*)d_in[7];
  const float* eW      = (const float*)d_in[8];
  const float* eb      = (const float*)d_in[9];
  const float* aW      = (const float*)d_in[10];
  const float* ab      = (const float*)d_in[11];
  const float* pW      = (const float*)d_in[12];
  const float* pb      = (const float*)d_in[13];

  // ws: [0,1024) counters (wcnt 64 | scnt 64, zeroed each call) | w | e | a | partials
  unsigned* wcnt = (unsigned*)d_ws;
  unsigned* scnt = wcnt + 64;
  float* base    = (float*)d_ws + 256;
  float* w_ws    = base;
  float* e_ws    = w_ws + (size_t)BB * TT * 64;
  float* a_ws    = e_ws + (size_t)BB * TT * 64;
  float* part_ws = a_ws + (size_t)BB * TT * 64;

  hipMemsetAsync(d_ws, 0, 1024, stream);
  dkvmn_pipe<<<dim3(NBLK), dim3(256), 0, stream>>>(
      skills, responses, k_emb, v_emb, Mk, Mv0, fW, fb, eW, eb, aW, ab, pW, pb,
      wcnt, scnt, w_ws, e_ws, a_ws, part_ws, (float*)d_out);
}

// Round 11
// 186.607 us; speedup vs baseline: 1.1129x; 1.1129x over previous
//
#include <hip/hip_runtime.h>
#include <hip/hip_bf16.h>
#include <stdint.h>

#define NSK 1000
#define TT  200
#define BB  64
#define CH  8      // scan chunk (steps)
#define SW  8      // scan waves (waves 0..7)
#define RW  8      // Mv rows per scan wave

__device__ __forceinline__ float lane_bcast(float v, int l) {
  return __uint_as_float(__builtin_amdgcn_readlane(__float_as_uint(v), l));
}
__device__ __forceinline__ unsigned ulane_bcast(unsigned v, int l) {
  return __builtin_amdgcn_readlane(v, l);
}
__device__ __forceinline__ float frcp(float x) { return __builtin_amdgcn_rcpf(x); }
__device__ __forceinline__ float sigm(float x) { return frcp(1.f + __expf(-x)); }
__device__ __forceinline__ float tanh_fast(float x) {
  return fmaf(-2.f, frcp(1.f + __expf(2.f * x)), 1.f);   // 1 - 2/(1+e^2x)
}

typedef _Float16 half2v __attribute__((ext_vector_type(2)));
union H2U { unsigned u; half2v h; };
__device__ __forceinline__ unsigned pack2h(float a, float b) {
  H2U x; x.h = (half2v){(_Float16)a, (_Float16)b}; return x.u;
}
__device__ __forceinline__ float dot2h(unsigned sp, unsigned wp, float acc) {
#if __has_builtin(__builtin_amdgcn_fdot2)
  H2U s, w; s.u = sp; w.u = wp;
  return __builtin_amdgcn_fdot2(s.h, w.h, acc, false);
#else
  H2U s, w; s.u = sp; w.u = wp;
  return fmaf((float)s.h.y, (float)w.h.y, fmaf((float)s.h.x, (float)w.h.x, acc));
#endif
}
__device__ __forceinline__ unsigned pack_pairs(float v) {
  const int lane = threadIdx.x & 63;
  float a = __shfl(v, 2 * lane);       // lanes 0..31 cover all 32 pairs
  float b = __shfl(v, 2 * lane + 1);
  return pack2h(a, b);
}

// ---- phase A: group of N rows (rows rbase+16*i), weights from LDS (stride-40 swizzle)
template<int N>
__device__ __forceinline__ void wea_group(
    const unsigned* smem, const int* __restrict__ skills,
    const int* __restrict__ responses, const float* __restrict__ k_emb,
    const float* __restrict__ v_emb, float ebl, float abl,
    int base, int rbase, int lane,
    float* __restrict__ w_ws, float* __restrict__ e_ws, float* __restrict__ a_ws)
{
  float kv[N], vv[N];
  #pragma unroll
  for (int i = 0; i < N; ++i) {
    const int r  = rbase + 16 * i;
    const int rc = (r < TT) ? r : (TT - 1);
    const int sk = skills[base + rc];
    int rr = responses[base + rc]; rr = (rr > -1) ? rr : 0;   // masked_r
    kv[i] = k_emb[(size_t)sk * 64 + lane];
    vv[i] = v_emb[(size_t)(sk + NSK * rr) * 64 + lane];
  }
  unsigned kp[N], vp[N];
  #pragma unroll
  for (int i = 0; i < N; ++i) { kp[i] = pack_pairs(kv[i]); vp[i] = pack_pairs(vv[i]); }

  float accK[N] = {}, accE[N] = {}, accA[N] = {};
  #pragma unroll 1
  for (int h = 0; h < 2; ++h) {                    // halves: 4 uint4 chunks (32 dims)
    uint4 qm[4], qe[4], qa[4];
    #pragma unroll
    for (int c = 0; c < 4; ++c) {
      const int off = lane * 40 + (((h * 4 + c) + lane) & 7) * 4;
      qm[c] = *(const uint4*)&smem[off];
      qe[c] = *(const uint4*)&smem[2560 + off];
      qa[c] = *(const uint4*)&smem[5120 + off];
    }
    #pragma unroll
    for (int i = 0; i < N; ++i) {
      #pragma unroll
      for (int c = 0; c < 4; ++c) {
        const unsigned um[4] = {qm[c].x, qm[c].y, qm[c].z, qm[c].w};
        const unsigned ue[4] = {qe[c].x, qe[c].y, qe[c].z, qe[c].w};
        const unsigned ua[4] = {qa[c].x, qa[c].y, qa[c].z, qa[c].w};
        #pragma unroll
        for (int m = 0; m < 4; ++m) {
          const int idx = (h * 4 + c) * 4 + m;     // pair index 0..31
          const unsigned spk = ulane_bcast(kp[i], idx);
          const unsigned spv = ulane_bcast(vp[i], idx);
          accK[i] = dot2h(spk, um[m], accK[i]);
          accE[i] = dot2h(spv, ue[m], accE[i]);
          accA[i] = dot2h(spv, ua[m], accA[i]);
        }
      }
    }
  }
  #pragma unroll
  for (int i = 0; i < N; ++i) {
    const int r = rbase + 16 * i;
    float mx = accK[i];
    #pragma unroll
    for (int off = 32; off; off >>= 1) mx = fmaxf(mx, __shfl_xor(mx, off));
    float ex = __expf(accK[i] - mx);
    float sm = ex;
    #pragma unroll
    for (int off = 32; off; off >>= 1) sm += __shfl_xor(sm, off);
    if (r < TT) {
      w_ws[(size_t)(base + r) * 64 + lane] = ex * frcp(sm);
      e_ws[(size_t)(base + r) * 64 + lane] = sigm(accE[i] + ebl);
      a_ws[(size_t)(base + r) * 64 + lane] = tanh_fast(accA[i] + abl);
    }
  }
}

// ---- scan helpers ----
__device__ __forceinline__ void load_chunk(
    const float* __restrict__ wr, const float* __restrict__ er,
    const float* __restrict__ ar, int t0, int wl, int lane,
    float* wb, float* ebf, float* abf)
{
  #pragma unroll
  for (int k = 0; k < CH; ++k) {
    wb[k]  = wr[(t0 + k) * 64 + wl];
    ebf[k] = er[(t0 + k) * 64 + lane];
    abf[k] = ar[(t0 + k) * 64 + lane];
  }
}

__device__ __forceinline__ void compute_chunk(
    float* Mv, const float* wb, const float* ebf, const float* abf,
    float* __restrict__ red, int wave, int lane)
{
  #pragma unroll
  for (int k = 0; k < CH; ++k) {
    const float wv = wb[k], ev = ebf[k], av = abf[k];
    float rp = 0.f;
    #pragma unroll
    for (int i = 0; i < RW; ++i) {
      float wm = lane_bcast(wv, i);        // w[m0+i] sits in lane i (0..7)
      rp = fmaf(wm, Mv[i], rp);            // read uses PRE-update Mv
      float tp = fmaf(-ev, Mv[i], av);     // a - e*Mv
      Mv[i] = fmaf(wm, tp, Mv[i]);         // Mv += w*(a - e*Mv)
    }
    red[k * 512 + wave * 64 + lane] = rp;  // per-wave partial -> LDS
  }
}

// reduce wave (k2 = wave-8) sums the 8 per-wave partials of step k2 -> read_ws
__device__ __forceinline__ void reduce_step(
    const float* __restrict__ red, int ch, int k2, int lane, int base,
    float* __restrict__ read_ws)
{
  const float* r = red + k2 * 512;
  float v = ((r[0 * 64 + lane] + r[1 * 64 + lane]) + (r[2 * 64 + lane] + r[3 * 64 + lane]))
          + ((r[4 * 64 + lane] + r[5 * 64 + lane]) + (r[6 * 64 + lane] + r[7 * 64 + lane]));
  read_ws[(size_t)(base + ch * CH + k2) * 64 + lane] = v;
}

// ---- phase C: group of N outputs (o = obase+16*i, t = o+1)
template<int N>
__device__ __forceinline__ void fp_group(
    const unsigned* smem, const int* __restrict__ skills,
    const float* __restrict__ k_emb, const float* __restrict__ read_ws,
    float fbl, float pwl, float pb0, int base, int obase, int lane, int b,
    float* __restrict__ out)
{
  float rv[N], kc[N];
  #pragma unroll
  for (int i = 0; i < N; ++i) {
    const int o  = obase + 16 * i;
    const int oc = (o < TT - 1) ? o : (TT - 2);
    const int t  = oc + 1;
    rv[i] = read_ws[(size_t)(base + t) * 64 + lane];
    kc[i] = k_emb[(size_t)skills[base + t] * 64 + lane];
  }
  unsigned rvp[N], kvp[N];
  #pragma unroll
  for (int i = 0; i < N; ++i) { rvp[i] = pack_pairs(rv[i]); kvp[i] = pack_pairs(kc[i]); }

  float acc[N];
  #pragma unroll
  for (int i = 0; i < N; ++i) acc[i] = fbl;
  #pragma unroll 1
  for (int h = 0; h < 4; ++h) {                    // quarters: 4 uint4 (32 inputs)
    uint4 qf[4];
    #pragma unroll
    for (int c = 0; c < 4; ++c)
      qf[c] = *(const uint4*)&smem[lane * 72 + (((h * 4 + c) + lane) & 15) * 4];
    #pragma unroll
    for (int i = 0; i < N; ++i) {
      #pragma unroll
      for (int c = 0; c < 4; ++c) {
        const unsigned uu[4] = {qf[c].x, qf[c].y, qf[c].z, qf[c].w};
        #pragma unroll
        for (int m = 0; m < 4; ++m) {
          const int idx = (h * 4 + c) * 4 + m;     // pair index 0..63
          const unsigned sp = (idx < 32) ? ulane_bcast(rvp[i], idx)
                                         : ulane_bcast(kvp[i], idx - 32);
          acc[i] = dot2h(sp, uu[m], acc[i]);
        }
      }
    }
  }
  #pragma unroll
  for (int i = 0; i < N; ++i) {
    const int o = obase + 16 * i;
    float f = tanh_fast(acc[i]) * pwl;
    #pragma unroll
    for (int off = 32; off; off >>= 1) f += __shfl_xor(f, off);
    if (lane == 0 && o < TT - 1) out[(size_t)b * (TT - 1) + o] = sigm(f + pb0);
  }
}

// One block per batch, 1024 threads (16 waves, 4/SIMD). All phases in-block:
// no atomics, no device fences -- intermediates stay warm in the block's own L1/L2.
__global__ __launch_bounds__(1024, 4) void dkvmn_batch(
    const int* __restrict__ skills, const int* __restrict__ responses,
    const float* __restrict__ k_emb, const float* __restrict__ v_emb,
    const float* __restrict__ Mk, const float* __restrict__ Mv0,
    const float* __restrict__ fW, const float* __restrict__ fb,
    const float* __restrict__ eW, const float* __restrict__ eb,
    const float* __restrict__ aW, const float* __restrict__ ab,
    const float* __restrict__ pW, const float* __restrict__ pb,
    float* __restrict__ w_ws, float* __restrict__ e_ws, float* __restrict__ a_ws,
    float* __restrict__ read_ws, float* __restrict__ out)
{
  __shared__ unsigned smem[7680];                  // 30720 B: A weights | B red | C fW
  const int tid = threadIdx.x;
  const int wave = tid >> 6, lane = tid & 63;
  const int b = blockIdx.x, base = b * TT;

  // ---------------- Phase A: wea for this batch's 200 rows ----------------
  for (int ch = tid; ch < 1536; ch += 1024) {      // f16-pack Mk/eW/aW, stride 40
    const int mat = ch >> 9, rem = ch & 511;
    const int j = rem >> 3, cc = rem & 7;
    const float4* src = (mat == 0) ? (const float4*)Mk
                      : (mat == 1) ? (const float4*)eW : (const float4*)aW;
    const float4 f0 = src[j * 16 + cc * 2];
    const float4 f1 = src[j * 16 + cc * 2 + 1];
    uint4 pk;
    pk.x = pack2h(f0.x, f0.y); pk.y = pack2h(f0.z, f0.w);
    pk.z = pack2h(f1.x, f1.y); pk.w = pack2h(f1.z, f1.w);
    *(uint4*)&smem[mat * 2560 + j * 40 + ((cc + j) & 7) * 4] = pk;
  }
  __syncthreads();
  {
    const float ebl = eb[lane], abl = ab[lane];
    wea_group<7>(smem, skills, responses, k_emb, v_emb, ebl, abl,
                 base, wave, lane, w_ws, e_ws, a_ws);
    wea_group<6>(smem, skills, responses, k_emb, v_emb, ebl, abl,
                 base, wave + 112, lane, w_ws, e_ws, a_ws);
  }
  __threadfence_block();
  __syncthreads();

  // ---------------- Phase B: scan (waves 0..7), reduce (waves 8..15) ----------------
  {
    const float* wr = w_ws + (size_t)base * 64;
    const float* er = e_ws + (size_t)base * 64;
    const float* ar = a_ws + (size_t)base * 64;
    float* redf = (float*)smem;                    // 8*512 floats = 16 KB
    const int m0 = wave * RW;                      // scan waves only
    const int wl = m0 + (lane & (RW - 1));
    const int k2 = wave - SW;                      // reduce waves only

    float Mv[RW];
    float wb0[CH], eb0[CH], ab0[CH];
    float wb1[CH], eb1[CH], ab1[CH];
    if (wave < SW) {
      #pragma unroll
      for (int i = 0; i < RW; ++i) Mv[i] = Mv0[(size_t)(m0 + i) * 64 + lane];
      load_chunk(wr, er, ar, 0, wl, lane, wb0, eb0, ab0);
    }
    for (int ch = 0; ch < TT / CH; ch += 2) {
      if (wave < SW) {
        if (ch + 1 < TT / CH) load_chunk(wr, er, ar, (ch + 1) * CH, wl, lane, wb1, eb1, ab1);
        compute_chunk(Mv, wb0, eb0, ab0, redf, wave, lane);
      }
      __syncthreads();                             // red ready
      if (wave >= SW) reduce_step(redf, ch, k2, lane, base, read_ws);
      __syncthreads();                             // red consumed
      if (ch + 1 < TT / CH) {
        if (wave < SW) {
          if (ch + 2 < TT / CH) load_chunk(wr, er, ar, (ch + 2) * CH, wl, lane, wb0, eb0, ab0);
          compute_chunk(Mv, wb1, eb1, ab1, redf, wave, lane);
        }
        __syncthreads();
        if (wave >= SW) reduce_step(redf, ch + 1, k2, lane, base, read_ws);
        __syncthreads();
      }
    }
  }

  // ---------------- Phase C: fp for this batch's 199 outputs ----------------
  for (int ch = tid; ch < 1024; ch += 1024) {      // restage fW f16, stride 72
    const int j = ch >> 4, cc = ch & 15;
    const float4 f0 = ((const float4*)fW)[j * 32 + cc * 2];
    const float4 f1 = ((const float4*)fW)[j * 32 + cc * 2 + 1];
    uint4 pk;
    pk.x = pack2h(f0.x, f0.y); pk.y = pack2h(f0.z, f0.w);
    pk.z = pack2h(f1.x, f1.y); pk.w = pack2h(f1.z, f1.w);
    *(uint4*)&smem[j * 72 + ((cc + j) & 15) * 4] = pk;
  }
  __threadfence_block();                           // read_ws visible to all waves
  __syncthreads();
  {
    const float fbl = fb[lane], pwl = pW[lane], pb0 = pb[0];
    fp_group<7>(smem, skills, k_emb, read_ws, fbl, pwl, pb0, base, wave, lane, b, out);
    fp_group<6>(smem, skills, k_emb, read_ws, fbl, pwl, pb0, base, wave + 112, lane, b, out);
  }
}

extern "C" void kernel_launch(void* const* d_in, const int* in_sizes, int n_in,
                              void* d_out, int out_size, void* d_ws, size_t ws_size,
                              hipStream_t stream) {
  const int* skills    = (const int*)d_in[0];
  const int* responses = (const int*)d_in[1];
  const float* k_emb   = (const float*)d_in[2];
  const float* v_emb   = (const float*)d_in[3];
  const float* Mk      = (const float*)d_in[4];
  const float* Mv0     = (const float*)d_in[5];
  const float* fW      = (const float*)d_in[6];
  const float* fb      = (const float*)d_in[7];
  const float* eW      = (const float*)d_in[8];
  const float* eb      = (const float*)d_in[9];
  const float* aW      = (const float*)d_in[10];
  const float* ab      = (const float*)d_in[11];
  const float* pW      = (const float*)d_in[12];
  const float* pb      = (const float*)d_in[13];

  // fp32 scratch: w | e | a | read  (B*T*64 each) ~= 13.1 MB; no counters, no memset
  float* w_ws    = (float*)d_ws;
  float* e_ws    = w_ws + (size_t)BB * TT * 64;
  float* a_ws    = e_ws + (size_t)BB * TT * 64;
  float* read_ws = a_ws + (size_t)BB * TT * 64;

  dkvmn_batch<<<dim3(BB), dim3(1024), 0, stream>>>(
      skills, responses, k_emb, v_emb, Mk, Mv0, fW, fb, eW, eb, aW, ab, pW, pb,
      w_ws, e_ws, a_ws, read_ws, (float*)d_out);
}